// Round 1
// baseline (292.751 us; speedup 1.0000x reference)
//
#include <hip/hip_runtime.h>
#include <hip/hip_bf16.h>

#define CM 256
#define CZ 128
#define CH 32
#define SS 128
#define NN 384

typedef short bf16x8 __attribute__((ext_vector_type(8)));
typedef float f32x4 __attribute__((ext_vector_type(4)));
typedef unsigned short us4 __attribute__((ext_vector_type(4)));
typedef unsigned short us8 __attribute__((ext_vector_type(8)));

__device__ __forceinline__ unsigned short f2bf(float f) {
    __hip_bfloat16 h = __float2bfloat16(f);
    return __builtin_bit_cast(unsigned short, h);
}

// ---------------- K0: WoT[n][k] = bf16(Wo[k][n]) ----------------
__global__ void k0_wo_t(const float* __restrict__ Wo, unsigned short* __restrict__ WoT) {
    int n = blockIdx.x;  // 0..127
    for (int k = threadIdx.x; k < CH * CH; k += blockDim.x) {
        WoT[n * (CH * CH) + k] = f2bf(Wo[(size_t)k * CZ + n]);
    }
}

// ---------------- K1: LayerNorm + projections, transposed bf16 store ----------------
// grid (S/32, N). Block (s0, i): 32 s-rows of column i.
// Lt[(i*32+c)][s] = (mnorm @ Wl + bl)[s,i,c] / 128 ; Rt[(i*32+d)][s] = (mnorm @ Wr + br)[s,i,d]
__global__ __launch_bounds__(256) void k1_ln_proj(
    const float* __restrict__ msa, const float* __restrict__ g, const float* __restrict__ bta,
    const float* __restrict__ Wl, const float* __restrict__ bl,
    const float* __restrict__ Wr, const float* __restrict__ br,
    unsigned short* __restrict__ Lt, unsigned short* __restrict__ Rt)
{
    __shared__ unsigned short A_lds[32][264];  // [s-row][k], +8 pad
    __shared__ unsigned short B_lds[64][264];  // [n][k]  (n<32: Wl col, else Wr col)
    __shared__ float red[32][8][2];
    __shared__ float stats[32][2];

    const int s0 = blockIdx.x * 32;
    const int i  = blockIdx.y;
    const int t  = threadIdx.x;
    const int r = t >> 3, oct = t & 7;

    const float* row = msa + ((size_t)(s0 + r) * NN + i) * CM;
    float4 v[8];
    float sum = 0.f, sq = 0.f;
#pragma unroll
    for (int u = 0; u < 8; u++) {
        v[u] = ((const float4*)row)[oct * 8 + u];
        sum += v[u].x + v[u].y + v[u].z + v[u].w;
        sq  += v[u].x * v[u].x + v[u].y * v[u].y + v[u].z * v[u].z + v[u].w * v[u].w;
    }
    red[r][oct][0] = sum; red[r][oct][1] = sq;
    __syncthreads();
    if (t < 32) {
        float s = 0.f, q = 0.f;
#pragma unroll
        for (int u = 0; u < 8; u++) { s += red[t][u][0]; q += red[t][u][1]; }
        float mu = s * (1.f / CM);
        float var = q * (1.f / CM) - mu * mu;
        stats[t][0] = mu;
        stats[t][1] = rsqrtf(var + 1e-5f);
    }
    __syncthreads();
    const float mu = stats[r][0], rs = stats[r][1];
#pragma unroll
    for (int u = 0; u < 8; u++) {
        int k0 = oct * 32 + u * 4;
        float4 gv = ((const float4*)g)[k0 >> 2];
        float4 bv = ((const float4*)bta)[k0 >> 2];
        us4 pk;
        pk[0] = f2bf((v[u].x - mu) * rs * gv.x + bv.x);
        pk[1] = f2bf((v[u].y - mu) * rs * gv.y + bv.y);
        pk[2] = f2bf((v[u].z - mu) * rs * gv.z + bv.z);
        pk[3] = f2bf((v[u].w - mu) * rs * gv.w + bv.w);
        *(us4*)&A_lds[r][k0] = pk;
    }
    {   // B_lds[n][k]
        int n = t >> 2, q4 = t & 3;
        const float* W = (n < 32) ? Wl : Wr;
        int ch = n & 31;
        for (int k = q4 * 64; k < q4 * 64 + 64; k++) {
            B_lds[n][k] = f2bf(W[(size_t)k * CH + ch]);
        }
    }
    __syncthreads();

    const int wv = t >> 6, lane = t & 63;
    const int lr = lane & 15, lg = lane >> 4;
    const int mtile = wv & 1;
    const int nbase = (wv >> 1) * 32;
    f32x4 acc[2];
    acc[0] = (f32x4){0.f, 0.f, 0.f, 0.f};
    acc[1] = (f32x4){0.f, 0.f, 0.f, 0.f};
#pragma unroll
    for (int ks = 0; ks < 8; ks++) {
        int ko = ks * 32 + lg * 8;
        bf16x8 a  = *(const bf16x8*)&A_lds[mtile * 16 + lr][ko];
        bf16x8 b0 = *(const bf16x8*)&B_lds[nbase + lr][ko];
        bf16x8 b1 = *(const bf16x8*)&B_lds[nbase + 16 + lr][ko];
        acc[0] = __builtin_amdgcn_mfma_f32_16x16x32_bf16(a, b0, acc[0], 0, 0, 0);
        acc[1] = __builtin_amdgcn_mfma_f32_16x16x32_bf16(a, b1, acc[1], 0, 0, 0);
    }
    const int mrow = mtile * 16 + lg * 4;  // + reg
#pragma unroll
    for (int half = 0; half < 2; half++) {
        int n = nbase + half * 16 + lr;     // wave-uniform side (nbase 0 => left, 32 => right)
        bool isL = (n < 32);
        int ch = n & 31;
        float bias  = isL ? bl[ch] : br[ch];
        float scale = isL ? (1.f / 128.f) : 1.f;   // fold 1/S into left; exact pow2 in bf16
        unsigned short* dst = (isL ? Lt : Rt) + (size_t)(i * CH + ch) * SS + s0 + mrow;
        us4 pk;
#pragma unroll
        for (int rg = 0; rg < 4; rg++)
            pk[rg] = f2bf((acc[half][rg] + bias) * scale);
        *(us4*)dst = pk;
    }
}

// ---------------- K2: fused GEMM1 (outer) + GEMM2 (@Wo) ----------------
#define TI 8
#define TJ 8
#define B_OFF 69632      // 256*136*2
#define WS_OFF 135168    // 256*264*2 (O region)
#define LDS_TOTAL 155648 // WS_OFF + 2*128*40*2

__global__ __launch_bounds__(512, 2) void k2_fused(
    const unsigned short* __restrict__ Lt, const unsigned short* __restrict__ Rt,
    const unsigned short* __restrict__ WoT, const float* __restrict__ bo,
    float* __restrict__ out)
{
    extern __shared__ char smem[];
    unsigned short* A = (unsigned short*)(smem);          // [256][136]
    unsigned short* B = (unsigned short*)(smem + B_OFF);  // [256][136]

    const int i0 = blockIdx.x * TI;
    const int j0 = blockIdx.y * TJ;
    const int t = threadIdx.x;

    // Phase 1 staging: contiguous 64KB tiles, padded LDS rows (stride 136)
    const unsigned short* gA = Lt + (size_t)i0 * CH * SS;
    const unsigned short* gB = Rt + (size_t)j0 * CH * SS;
#pragma unroll
    for (int it = 0; it < 8; it++) {
        int c  = it * 512 + t;          // 4096 16B-chunks per tile
        int rw = c >> 4, kc = c & 15;   // 16 chunks per 128-elem row
        *(us8*)(A + rw * 136 + kc * 8) = *(const us8*)(gA + rw * 128 + kc * 8);
        *(us8*)(B + rw * 136 + kc * 8) = *(const us8*)(gB + rw * 128 + kc * 8);
    }
    __syncthreads();

    const int wv = t >> 6, lane = t & 63;
    const int lr = lane & 15, lg = lane >> 4;
    const int m0 = (wv >> 2) * 128;   // wave's M range (2 x 128)
    const int n0 = (wv & 3) * 64;     // wave's N range (4 x 64)

    f32x4 acc[8][4];
#pragma unroll
    for (int mt = 0; mt < 8; mt++)
#pragma unroll
        for (int nt = 0; nt < 4; nt++)
            acc[mt][nt] = (f32x4){0.f, 0.f, 0.f, 0.f};

#pragma unroll
    for (int ks = 0; ks < 4; ks++) {
        int ko = ks * 32 + lg * 8;
        bf16x8 af[8], bfr[4];
#pragma unroll
        for (int mt = 0; mt < 8; mt++) af[mt]  = *(const bf16x8*)(A + (m0 + mt * 16 + lr) * 136 + ko);
#pragma unroll
        for (int nt = 0; nt < 4; nt++) bfr[nt] = *(const bf16x8*)(B + (n0 + nt * 16 + lr) * 136 + ko);
#pragma unroll
        for (int mt = 0; mt < 8; mt++)
#pragma unroll
            for (int nt = 0; nt < 4; nt++)
                acc[mt][nt] = __builtin_amdgcn_mfma_f32_16x16x32_bf16(af[mt], bfr[nt], acc[mt][nt], 0, 0, 0);
    }
    __syncthreads();  // A/B reads complete; LDS is repurposed below

    // O[row=ii*32+c][col=jj*32+d] bf16, stride 264
    unsigned short* O = (unsigned short*)(smem);
#pragma unroll
    for (int mt = 0; mt < 8; mt++)
#pragma unroll
        for (int nt = 0; nt < 4; nt++)
#pragma unroll
            for (int rg = 0; rg < 4; rg++) {
                int rw = m0 + mt * 16 + lg * 4 + rg;
                int cl = n0 + nt * 16 + lr;
                O[rw * 264 + cl] = f2bf(acc[mt][nt][rg]);
            }

    // stage Wo k-chunk 0: WS[buf][n][klocal], stride 40 (pad)
    unsigned short* WS = (unsigned short*)(smem + WS_OFF);
    {
        int n = t >> 2, pt = t & 3;
        *(us8*)(WS + n * 40 + pt * 8) = *(const us8*)(WoT + (size_t)n * 1024 + pt * 8);
    }
    __syncthreads();

    // Phase 2: M=64 pairs, N=128, K=1024
    const int p0 = (wv & 3) * 16;
    const int nb = (wv >> 2) * 64;
    const int p  = p0 + lr;
    const int ii = p >> 3, jj = p & 7;
    const unsigned short* Orow = O + (ii * 32) * 264 + jj * 32 + lg * 8;

    f32x4 acc2[4];
#pragma unroll
    for (int nt = 0; nt < 4; nt++) acc2[nt] = (f32x4){0.f, 0.f, 0.f, 0.f};

    for (int kk = 0; kk < 32; kk++) {
        int cur = kk & 1;
        if (kk < 31) {  // prefetch next Wo chunk into other buffer
            int n = t >> 2, pt = t & 3;
            *(us8*)(WS + (cur ^ 1) * 5120 + n * 40 + pt * 8) =
                *(const us8*)(WoT + (size_t)n * 1024 + (kk + 1) * 32 + pt * 8);
        }
        bf16x8 a2 = *(const bf16x8*)(Orow + kk * 264);
        const unsigned short* wb = WS + cur * 5120 + lg * 8;
#pragma unroll
        for (int nt = 0; nt < 4; nt++) {
            bf16x8 b2 = *(const bf16x8*)(wb + (nb + nt * 16 + lr) * 40);
            acc2[nt] = __builtin_amdgcn_mfma_f32_16x16x32_bf16(a2, b2, acc2[nt], 0, 0, 0);
        }
        __syncthreads();
    }

#pragma unroll
    for (int nt = 0; nt < 4; nt++) {
        int z = nb + nt * 16 + lr;
        float bz = bo[z];
#pragma unroll
        for (int rg = 0; rg < 4; rg++) {
            int pr = p0 + lg * 4 + rg;
            int gi = i0 + (pr >> 3), gj = j0 + (pr & 7);
            out[((size_t)gi * NN + gj) * CZ + z] = acc2[nt][rg] + bz;
        }
    }
}

extern "C" void kernel_launch(void* const* d_in, const int* in_sizes, int n_in,
                              void* d_out, int out_size, void* d_ws, size_t ws_size,
                              hipStream_t stream) {
    const float* msa  = (const float*)d_in[0];
    const float* ln_g = (const float*)d_in[1];
    const float* ln_b = (const float*)d_in[2];
    const float* Wl   = (const float*)d_in[3];
    const float* bl   = (const float*)d_in[4];
    const float* Wr   = (const float*)d_in[5];
    const float* br   = (const float*)d_in[6];
    const float* Wo   = (const float*)d_in[7];
    const float* bo   = (const float*)d_in[8];
    float* out = (float*)d_out;

    unsigned short* Lt  = (unsigned short*)d_ws;                 // [12288][128] bf16
    unsigned short* Rt  = Lt + (size_t)NN * CH * SS;             // [12288][128] bf16
    unsigned short* WoT = Rt + (size_t)NN * CH * SS;             // [128][1024] bf16

    hipFuncSetAttribute((const void*)k2_fused,
                        hipFuncAttributeMaxDynamicSharedMemorySize, LDS_TOTAL);

    k0_wo_t<<<dim3(CZ), dim3(256), 0, stream>>>(Wo, WoT);
    k1_ln_proj<<<dim3(SS / 32, NN), dim3(256), 0, stream>>>(msa, ln_g, ln_b, Wl, bl, Wr, br, Lt, Rt);
    k2_fused<<<dim3(NN / TI, NN / TJ), dim3(512), LDS_TOTAL, stream>>>(Lt, Rt, WoT, bo, out);
}